// Round 5
// baseline (172.675 us; speedup 1.0000x reference)
//
#include <hip/hip_runtime.h>
#include <hip/hip_bf16.h>
#include <cstdint>

#define BB 32
#define LD 2048
#define LQ 512
#define DD 256
#define BM 128
#define BN 128
#define BK 64

typedef _Float16 half8 __attribute__((ext_vector_type(8)));
typedef _Float16 half4 __attribute__((ext_vector_type(4)));
typedef float float4v __attribute__((ext_vector_type(4)));

// tanh(x) = 1 - 2/(exp2(2*log2e*x)+1); v_exp_f32 + v_rcp_f32. Saturates correctly at +-inf.
__device__ __forceinline__ float tanh_fast(float x) {
    float t = __builtin_amdgcn_exp2f(x * 2.885390081777927f); // 2*log2(e)
    float r = __builtin_amdgcn_rcpf(t + 1.0f);
    return fmaf(-2.0f, r, 1.0f);
}

// K1: per-batch tanh(Q Doc^T), fused row/col sums -> PARTIAL logits (no atomics, no memset).
// 128x128 tile, 256 threads (4 waves, 64x64 quadrants), BK=64, fp32 fetch with in-register
// cvt->f16 during LDS staging. REGISTER-PREFETCH PIPELINE: global loads for iter kk+1 are
// issued right after the staging barrier of iter kk and consumed (cvt+ds_write) next iter,
// so the vmcnt wait lands after the MFMA section instead of at the barrier (the m97-structure
// stall). Regs: ~145 VGPR + 64 AGPR -> 2 waves/SIMD = 2 blocks/CU, same as R2's measured 25%.
// LDS XOR-swizzle (0 conflicts measured): 8-f16 group g of row r at phys chunk g^(r&7).
__global__ __launch_bounds__(256) void k1(const float* __restrict__ qsrc,
                                          const float* __restrict__ dsrc,
                                          float* __restrict__ pa,   // [4][B][LD] col-sum partials
                                          float* __restrict__ pb) { // [16][B][LQ] row-sum partials
    __shared__ _Float16 sQ[BM * BK]; // 16KB
    __shared__ _Float16 sD[BN * BK]; // 16KB
    __shared__ float srow[BM][2];
    __shared__ float scol[BN][2];
    const int bq = blockIdx.x, bt = blockIdx.y, b = blockIdx.z;
    const int tid = threadIdx.x;
    const int lane = tid & 63;
    const int wave = tid >> 6;
    const int r16 = lane & 15;
    const int q4 = lane >> 4;
    const int mb = (wave >> 1) * 64, nb = (wave & 1) * 64;

    float4v acc[4][4];
    float4v zero = {0.f, 0.f, 0.f, 0.f};
#pragma unroll
    for (int m = 0; m < 4; m++)
#pragma unroll
        for (int n = 0; n < 4; n++) acc[m][n] = zero;

    // staging map: thread -> (rows r0+16i, float4 col c) of the 128x64 fp32 tile
    const int r0 = tid >> 4;              // 0..15
    const int c = tid & 15;               // float4 within row (64 floats)
    const int c2 = c >> 1, hlf = c & 1;   // 8-f16 logical group + half
    const int p = c2 ^ (r0 & 7);          // (r0+16i)&7 == r0&7
    const int ldsoff = r0 * BK + p * 8 + hlf * 4;
    const float* Qf = qsrc + ((size_t)b * LQ + bq * BM + r0) * DD + 4 * c;
    const float* Df = dsrc + ((size_t)b * LD + bt * BN + r0) * DD + 4 * c;

    float4v rq[8], rd[8];
    // prologue: prefetch iter 0
#pragma unroll
    for (int i = 0; i < 8; i++) {
        rq[i] = *(const float4v*)(Qf + (size_t)i * 16 * DD);
        rd[i] = *(const float4v*)(Df + (size_t)i * 16 * DD);
    }

    for (int kk4 = 0; kk4 < 4; kk4++) {
        __syncthreads(); // previous iteration's LDS reads done
#pragma unroll
        for (int i = 0; i < 8; i++) {
            half4 h = {(_Float16)rq[i][0], (_Float16)rq[i][1], (_Float16)rq[i][2], (_Float16)rq[i][3]};
            *(half4*)(&sQ[ldsoff + i * 16 * BK]) = h;
            half4 h2 = {(_Float16)rd[i][0], (_Float16)rd[i][1], (_Float16)rd[i][2], (_Float16)rd[i][3]};
            *(half4*)(&sD[ldsoff + i * 16 * BK]) = h2;
        }
        __syncthreads(); // staging visible

        // issue next iteration's global loads NOW; consumed at next iter's cvt,
        // so their latency overlaps the MFMA section below.
        if (kk4 < 3) {
            const int kk = (kk4 + 1) * BK;
#pragma unroll
            for (int i = 0; i < 8; i++) {
                rq[i] = *(const float4v*)(Qf + kk + (size_t)i * 16 * DD);
                rd[i] = *(const float4v*)(Df + kk + (size_t)i * 16 * DD);
            }
        }

#pragma unroll
        for (int kk2 = 0; kk2 < 2; kk2++) {
            const int sw = ((4 * kk2 + q4) ^ (r16 & 7)) * 8;
            half8 af[4], bf[4];
#pragma unroll
            for (int m = 0; m < 4; m++) af[m] = *(const half8*)(&sQ[(mb + 16 * m + r16) * BK + sw]);
#pragma unroll
            for (int n = 0; n < 4; n++) bf[n] = *(const half8*)(&sD[(nb + 16 * n + r16) * BK + sw]);
#pragma unroll
            for (int m = 0; m < 4; m++)
#pragma unroll
                for (int n = 0; n < 4; n++)
                    acc[m][n] = __builtin_amdgcn_mfma_f32_16x16x32_f16(af[m], bf[n], acc[m][n], 0, 0, 0);
        }
    }

    // Epilogue. C/D layout: row = 4*q4 + r, col = r16.
    float rsum[4][4];
    float csum[4];
#pragma unroll
    for (int m = 0; m < 4; m++)
#pragma unroll
        for (int r = 0; r < 4; r++) rsum[m][r] = 0.f;
#pragma unroll
    for (int n = 0; n < 4; n++) csum[n] = 0.f;

#pragma unroll
    for (int m = 0; m < 4; m++)
#pragma unroll
        for (int n = 0; n < 4; n++) {
            float t0 = tanh_fast(acc[m][n][0]);
            float t1 = tanh_fast(acc[m][n][1]);
            float t2 = tanh_fast(acc[m][n][2]);
            float t3 = tanh_fast(acc[m][n][3]);
            csum[n] += t0 + t1 + t2 + t3;
            rsum[m][0] += t0;
            rsum[m][1] += t1;
            rsum[m][2] += t2;
            rsum[m][3] += t3;
        }

#pragma unroll
    for (int m = 0; m < 4; m++) {
#pragma unroll
        for (int r = 0; r < 4; r++) {
            float v = rsum[m][r];
            v += __shfl_xor(v, 1);
            v += __shfl_xor(v, 2);
            v += __shfl_xor(v, 4);
            v += __shfl_xor(v, 8);
            rsum[m][r] = v;
        }
        if (r16 < 4) {
            float v = (r16 == 0) ? rsum[m][0] : (r16 == 1) ? rsum[m][1] : (r16 == 2) ? rsum[m][2] : rsum[m][3];
            srow[mb + 16 * m + 4 * q4 + r16][wave & 1] = v;
        }
    }
#pragma unroll
    for (int n = 0; n < 4; n++) {
        float v = csum[n];
        v += __shfl_xor(v, 16);
        v += __shfl_xor(v, 32);
        if (lane < 16) scol[nb + 16 * n + lane][wave >> 1] = v;
    }
    __syncthreads();
    if (tid < 128) {
        float v = srow[tid][0] + srow[tid][1];
        pb[((size_t)bt * BB + b) * LQ + bq * BM + tid] = v;
        float u = scol[tid][0] + scol[tid][1];
        pa[((size_t)bq * BB + b) * LD + bt * BN + tid] = u;
    }
}

// K2: sum partials -> masked renormalized softmax. Blocks 0..31: alpha rows (n=2048, also
// zero d_out slice for k3's atomics); blocks 32..63: beta rows (n=512).
__global__ __launch_bounds__(256) void k2(const float* __restrict__ pa, const float* __restrict__ pb,
                                          const float* __restrict__ dmask, const float* __restrict__ qmask,
                                          float* __restrict__ alpha, float* __restrict__ beta,
                                          float* __restrict__ out) {
    __shared__ float sl[2048];
    __shared__ float sm[4], ss[4];
    int blk = blockIdx.x, tid = threadIdx.x, lane = tid & 63, wave = tid >> 6;
    const float* mk;
    float* dst;
    int n;
    if (blk < BB) {
        int b = blk;
        out[b * 2 * DD + tid] = 0.f;          // zero d_out for k3
        out[b * 2 * DD + 256 + tid] = 0.f;
        n = LD;
        mk = dmask + b * LD;
        dst = alpha + b * LD;
        for (int i = tid; i < n; i += 256) {
            float s = 0.f;
#pragma unroll
            for (int j = 0; j < 4; j++) s += pa[((size_t)j * BB + b) * LD + i];
            sl[i] = s;
        }
    } else {
        int b = blk - BB;
        n = LQ;
        mk = qmask + b * LQ;
        dst = beta + b * LQ;
        for (int i = tid; i < n; i += 256) {
            float s = 0.f;
#pragma unroll
            for (int j = 0; j < 16; j++) s += pb[((size_t)j * BB + b) * LQ + i];
            sl[i] = s;
        }
    }
    __syncthreads();
    float mx = -3.0e38f;
    for (int i = tid; i < n; i += 256) mx = fmaxf(mx, sl[i]);
#pragma unroll
    for (int s = 1; s < 64; s <<= 1) mx = fmaxf(mx, __shfl_xor(mx, s));
    if (lane == 0) sm[wave] = mx;
    __syncthreads();
    mx = fmaxf(fmaxf(sm[0], sm[1]), fmaxf(sm[2], sm[3]));
    const float L2E = 1.4426950408889634f;
    float sum = 0.f;
    for (int i = tid; i < n; i += 256) {
        float e = __builtin_amdgcn_exp2f((sl[i] - mx) * L2E) * mk[i];
        sl[i] = e;
        sum += e;
    }
#pragma unroll
    for (int s = 1; s < 64; s <<= 1) sum += __shfl_xor(sum, s);
    if (lane == 0) ss[wave] = sum;
    __syncthreads();
    sum = ss[0] + ss[1] + ss[2] + ss[3];
    float inv = 1.0f / sum;
    for (int i = tid; i < n; i += 256) dst[i] = sl[i] * inv;
}

// K3: weighted pooling, fp32 sources, coalesced float4 loads. Block = (b, 128-position chunk).
// Thread (g=tid>>5, c=tid&31): owns d-slice [8c,8c+8), strides g over positions.
__global__ __launch_bounds__(256) void k3(const float* __restrict__ docf, const float* __restrict__ qryf,
                                          const float* __restrict__ alpha, const float* __restrict__ beta,
                                          float* __restrict__ out) {
    __shared__ float sm[8 * DD];
    int blk = blockIdx.x, tid = threadIdx.x;
    const float* srcf;
    const float* w;
    float* dst;
    if (blk < BB * 16) {
        int b = blk >> 4, ch = blk & 15;
        srcf = docf + ((size_t)b * LD + ch * 128) * DD;
        w = alpha + b * LD + ch * 128;
        dst = out + b * 2 * DD;
    } else {
        int k = blk - BB * 16;
        int b = k >> 2, ch = k & 3;
        srcf = qryf + ((size_t)b * LQ + ch * 128) * DD;
        w = beta + b * LQ + ch * 128;
        dst = out + b * 2 * DD + DD;
    }
    int g = tid >> 5, c = tid & 31;
    float acc[8];
#pragma unroll
    for (int j = 0; j < 8; j++) acc[j] = 0.f;
#pragma unroll
    for (int r = 0; r < 16; r++) {
        int t = r * 8 + g;
        float wt = w[t];
        const float4v* p = (const float4v*)(srcf + (size_t)t * DD + c * 8);
        float4v x0 = p[0], x1 = p[1];
#pragma unroll
        for (int j = 0; j < 4; j++) { acc[j] += wt * x0[j]; acc[4 + j] += wt * x1[j]; }
    }
#pragma unroll
    for (int j = 0; j < 8; j++) sm[g * DD + c * 8 + j] = acc[j];
    __syncthreads();
    float s = 0.f;
#pragma unroll
    for (int g2 = 0; g2 < 8; g2++) s += sm[g2 * DD + tid];
    atomicAdd(dst + tid, s);
}

extern "C" void kernel_launch(void* const* d_in, const int* in_sizes, int n_in,
                              void* d_out, int out_size, void* d_ws, size_t ws_size,
                              hipStream_t stream) {
    (void)in_sizes; (void)n_in; (void)out_size; (void)ws_size;
    const float* doc = (const float*)d_in[0];
    const float* qry = (const float*)d_in[1];
    const float* dmask = (const float*)d_in[2];
    const float* qmask = (const float*)d_in[3];
    float* out = (float*)d_out;

    float* pa = (float*)d_ws;                   // [4][B][LD]
    float* pb = pa + 4 * BB * LD;               // [16][B][LQ]
    float* alpha = pb + 16 * BB * LQ;           // [B][LD]
    float* beta = alpha + BB * LD;              // [B][LQ]

    k1<<<dim3(LQ / BM, LD / BN, BB), 256, 0, stream>>>(qry, doc, pa, pb);
    k2<<<2 * BB, 256, 0, stream>>>(pa, pb, dmask, qmask, alpha, beta, out);
    k3<<<BB * 16 + BB * 4, 256, 0, stream>>>(doc, qry, alpha, beta, out);
}

// Round 6
// 159.810 us; speedup vs baseline: 1.0805x; 1.0805x over previous
//
#include <hip/hip_runtime.h>
#include <hip/hip_bf16.h>
#include <cstdint>

#define BB 32
#define LD 2048
#define LQ 512
#define DD 256
#define BM 128
#define BN 128
#define BK 64

typedef _Float16 half8 __attribute__((ext_vector_type(8)));
typedef _Float16 half4 __attribute__((ext_vector_type(4)));
typedef float float4v __attribute__((ext_vector_type(4)));

// tanh(x) = 1 - 2/(exp2(2*log2e*x)+1); v_exp_f32 + v_rcp_f32. Saturates correctly at +-inf.
__device__ __forceinline__ float tanh_fast(float x) {
    float t = __builtin_amdgcn_exp2f(x * 2.885390081777927f); // 2*log2(e)
    float r = __builtin_amdgcn_rcpf(t + 1.0f);
    return fmaf(-2.0f, r, 1.0f);
}

// async 16B global->LDS; LDS dest = wave-uniform base + lane*16 (HW adds lane offset)
__device__ __forceinline__ void load_lds16(const void* g, void* s) {
    __builtin_amdgcn_global_load_lds((const __attribute__((address_space(1))) void*)g,
                                     (__attribute__((address_space(3))) void*)s, 16, 0, 0);
}

#define DOCN8 (BB * LD * DD / 8)
#define QRYN8 (BB * LQ * DD / 8)

// fp32 -> f16 convert of doc then query, one dispatch, 8 elems/thread. Pure streaming.
__global__ __launch_bounds__(256) void kconv(const float* __restrict__ doc,
                                             const float* __restrict__ qry,
                                             _Float16* __restrict__ dh,
                                             _Float16* __restrict__ qh) {
    int i = blockIdx.x * 256 + threadIdx.x;
    const float* src;
    _Float16* dst;
    int idx;
    if (i < DOCN8) { src = doc; dst = dh; idx = i; }
    else           { src = qry; dst = qh; idx = i - DOCN8; }
    const float4v* s = (const float4v*)src + (size_t)idx * 2;
    float4v a = s[0], c = s[1];
    half8 h = {(_Float16)a[0], (_Float16)a[1], (_Float16)a[2], (_Float16)a[3],
               (_Float16)c[0], (_Float16)c[1], (_Float16)c[2], (_Float16)c[3]};
    *((half8*)dst + idx) = h;
}

// K1 (R2-measured structure, 41.3 us): per-batch tanh(Q Doc^T), fused row/col sums ->
// PARTIAL logits (no atomics, no memsets). 128x128 tile, 4 waves (64x64 quadrants), BK=64.
// f16 path: global_load_lds 16B DMA staging (no VGPR round trip). LDS XOR-swizzle
// (0 conflicts measured R2): 8-f16 group g of row r at phys chunk g^(r&7), arranged via
// the lane->global map since the LDS side of global_load_lds is fixed to base+16*lane.
template <bool F16SRC>
__global__ __launch_bounds__(256) void k1(const void* __restrict__ qsrc,
                                          const void* __restrict__ dsrc,
                                          float* __restrict__ pa,   // [4][B][LD] col-sum partials
                                          float* __restrict__ pb) { // [16][B][LQ] row-sum partials
    __shared__ _Float16 sQ[BM * BK]; // 16KB
    __shared__ _Float16 sD[BN * BK]; // 16KB
    __shared__ float srow[BM][2];
    __shared__ float scol[BN][2];
    const int bq = blockIdx.x, bt = blockIdx.y, b = blockIdx.z;
    const int tid = threadIdx.x;
    const int lane = tid & 63;
    const int wave = tid >> 6;
    const int r16 = lane & 15;
    const int q4 = lane >> 4;
    const int mb = (wave >> 1) * 64, nb = (wave & 1) * 64;

    float4v acc[4][4];
    float4v zero = {0.f, 0.f, 0.f, 0.f};
#pragma unroll
    for (int m = 0; m < 4; m++)
#pragma unroll
        for (int n = 0; n < 4; n++) acc[m][n] = zero;

    // f16 DMA staging lane map: 1KB chunk = 8 rows x 128B; lane -> (row 8c+lrow, phys pos lane&7)
    const int lrow = lane >> 3;                 // 0..7
    const int lcol = ((lane & 7) ^ lrow) * 8;   // logical k offset (f16) for this phys pos

    for (int kk = 0; kk < DD; kk += BK) {
        __syncthreads(); // previous iteration's LDS reads done
        if constexpr (F16SRC) {
            const _Float16* Qh = (const _Float16*)qsrc + ((size_t)b * LQ + bq * BM) * DD;
            const _Float16* Dh = (const _Float16*)dsrc + ((size_t)b * LD + bt * BN) * DD;
#pragma unroll
            for (int j = 0; j < 4; j++) {
                int c = wave * 4 + j;           // chunk 0..15 (rows 8c..8c+7)
                int row = 8 * c + lrow;
                load_lds16(Qh + (size_t)row * DD + kk + lcol, &sQ[c * 512]);
                load_lds16(Dh + (size_t)row * DD + kk + lcol, &sD[c * 512]);
            }
        } else {
            const float* Qf = (const float*)qsrc + ((size_t)b * LQ + bq * BM) * DD;
            const float* Df = (const float*)dsrc + ((size_t)b * LD + bt * BN) * DD;
#pragma unroll
            for (int i = 0; i < 8; i++) {
                int f = tid + 256 * i;          // float4 id within 128x64 tile
                int row = f >> 4, c = f & 15;
                int c2 = c >> 1, hlf = c & 1;
                int p = c2 ^ (row & 7);
                float4v v = *(const float4v*)(Qf + (size_t)row * DD + kk + 4 * c);
                half4 h = {(_Float16)v[0], (_Float16)v[1], (_Float16)v[2], (_Float16)v[3]};
                *(half4*)(&sQ[row * BK + p * 8 + hlf * 4]) = h;
                float4v w = *(const float4v*)(Df + (size_t)row * DD + kk + 4 * c);
                half4 h2 = {(_Float16)w[0], (_Float16)w[1], (_Float16)w[2], (_Float16)w[3]};
                *(half4*)(&sD[row * BK + p * 8 + hlf * 4]) = h2;
            }
        }
        __syncthreads(); // staging complete

#pragma unroll
        for (int kk2 = 0; kk2 < 2; kk2++) {
            const int sw = ((4 * kk2 + q4) ^ (r16 & 7)) * 8;
            half8 af[4], bf[4];
#pragma unroll
            for (int m = 0; m < 4; m++) af[m] = *(const half8*)(&sQ[(mb + 16 * m + r16) * BK + sw]);
#pragma unroll
            for (int n = 0; n < 4; n++) bf[n] = *(const half8*)(&sD[(nb + 16 * n + r16) * BK + sw]);
#pragma unroll
            for (int m = 0; m < 4; m++)
#pragma unroll
                for (int n = 0; n < 4; n++)
                    acc[m][n] = __builtin_amdgcn_mfma_f32_16x16x32_f16(af[m], bf[n], acc[m][n], 0, 0, 0);
        }
    }

    // Epilogue. C/D layout: row = 4*q4 + r, col = r16.
    float rsum[4][4];
    float csum[4];
#pragma unroll
    for (int m = 0; m < 4; m++)
#pragma unroll
        for (int r = 0; r < 4; r++) rsum[m][r] = 0.f;
#pragma unroll
    for (int n = 0; n < 4; n++) csum[n] = 0.f;

#pragma unroll
    for (int m = 0; m < 4; m++)
#pragma unroll
        for (int n = 0; n < 4; n++) {
            float t0 = tanh_fast(acc[m][n][0]);
            float t1 = tanh_fast(acc[m][n][1]);
            float t2 = tanh_fast(acc[m][n][2]);
            float t3 = tanh_fast(acc[m][n][3]);
            csum[n] += t0 + t1 + t2 + t3;
            rsum[m][0] += t0;
            rsum[m][1] += t1;
            rsum[m][2] += t2;
            rsum[m][3] += t3;
        }

#pragma unroll
    for (int m = 0; m < 4; m++) {
#pragma unroll
        for (int r = 0; r < 4; r++) {
            float v = rsum[m][r];
            v += __shfl_xor(v, 1);
            v += __shfl_xor(v, 2);
            v += __shfl_xor(v, 4);
            v += __shfl_xor(v, 8);
            rsum[m][r] = v;
        }
        if (r16 < 4) {
            float v = (r16 == 0) ? rsum[m][0] : (r16 == 1) ? rsum[m][1] : (r16 == 2) ? rsum[m][2] : rsum[m][3];
            srow[mb + 16 * m + 4 * q4 + r16][wave & 1] = v;
        }
    }
#pragma unroll
    for (int n = 0; n < 4; n++) {
        float v = csum[n];
        v += __shfl_xor(v, 16);
        v += __shfl_xor(v, 32);
        if (lane < 16) scol[nb + 16 * n + lane][wave >> 1] = v;
    }
    __syncthreads();
    if (tid < 128) {
        float v = srow[tid][0] + srow[tid][1];
        pb[((size_t)bt * BB + b) * LQ + bq * BM + tid] = v;
        float u = scol[tid][0] + scol[tid][1];
        pa[((size_t)bq * BB + b) * LD + bt * BN + tid] = u;
    }
}

// K2: sum partials -> masked renormalized softmax. Blocks 0..31: alpha rows (n=2048, also
// zero d_out slice for k3's atomics); blocks 32..63: beta rows (n=512).
__global__ __launch_bounds__(256) void k2(const float* __restrict__ pa, const float* __restrict__ pb,
                                          const float* __restrict__ dmask, const float* __restrict__ qmask,
                                          float* __restrict__ alpha, float* __restrict__ beta,
                                          float* __restrict__ out) {
    __shared__ float sl[2048];
    __shared__ float sm[4], ss[4];
    int blk = blockIdx.x, tid = threadIdx.x, lane = tid & 63, wave = tid >> 6;
    const float* mk;
    float* dst;
    int n;
    if (blk < BB) {
        int b = blk;
        out[b * 2 * DD + tid] = 0.f;          // zero d_out for k3
        out[b * 2 * DD + 256 + tid] = 0.f;
        n = LD;
        mk = dmask + b * LD;
        dst = alpha + b * LD;
        for (int i = tid; i < n; i += 256) {
            float s = 0.f;
#pragma unroll
            for (int j = 0; j < 4; j++) s += pa[((size_t)j * BB + b) * LD + i];
            sl[i] = s;
        }
    } else {
        int b = blk - BB;
        n = LQ;
        mk = qmask + b * LQ;
        dst = beta + b * LQ;
        for (int i = tid; i < n; i += 256) {
            float s = 0.f;
#pragma unroll
            for (int j = 0; j < 16; j++) s += pb[((size_t)j * BB + b) * LQ + i];
            sl[i] = s;
        }
    }
    __syncthreads();
    float mx = -3.0e38f;
    for (int i = tid; i < n; i += 256) mx = fmaxf(mx, sl[i]);
#pragma unroll
    for (int s = 1; s < 64; s <<= 1) mx = fmaxf(mx, __shfl_xor(mx, s));
    if (lane == 0) sm[wave] = mx;
    __syncthreads();
    mx = fmaxf(fmaxf(sm[0], sm[1]), fmaxf(sm[2], sm[3]));
    const float L2E = 1.4426950408889634f;
    float sum = 0.f;
    for (int i = tid; i < n; i += 256) {
        float e = __builtin_amdgcn_exp2f((sl[i] - mx) * L2E) * mk[i];
        sl[i] = e;
        sum += e;
    }
#pragma unroll
    for (int s = 1; s < 64; s <<= 1) sum += __shfl_xor(sum, s);
    if (lane == 0) ss[wave] = sum;
    __syncthreads();
    sum = ss[0] + ss[1] + ss[2] + ss[3];
    float inv = 1.0f / sum;
    for (int i = tid; i < n; i += 256) dst[i] = sl[i] * inv;
}

// K3: weighted pooling. f16 sources when available (half the bytes), coalesced 16B loads.
// Block = (b, 128-position chunk); thread (g=tid>>5, c=tid&31) owns d-slice [8c,8c+8).
template <bool F16SRC>
__global__ __launch_bounds__(256) void k3(const float* __restrict__ docf, const float* __restrict__ qryf,
                                          const _Float16* __restrict__ dh, const _Float16* __restrict__ qh,
                                          const float* __restrict__ alpha, const float* __restrict__ beta,
                                          float* __restrict__ out) {
    __shared__ float sm[8 * DD];
    int blk = blockIdx.x, tid = threadIdx.x;
    const float* srcf;
    const _Float16* srch;
    const float* w;
    float* dst;
    if (blk < BB * 16) {
        int b = blk >> 4, ch = blk & 15;
        srcf = docf + ((size_t)b * LD + ch * 128) * DD;
        srch = dh + ((size_t)b * LD + ch * 128) * DD;
        w = alpha + b * LD + ch * 128;
        dst = out + b * 2 * DD;
    } else {
        int k = blk - BB * 16;
        int b = k >> 2, ch = k & 3;
        srcf = qryf + ((size_t)b * LQ + ch * 128) * DD;
        srch = qh + ((size_t)b * LQ + ch * 128) * DD;
        w = beta + b * LQ + ch * 128;
        dst = out + b * 2 * DD + DD;
    }
    int g = tid >> 5, c = tid & 31;
    float acc[8];
#pragma unroll
    for (int j = 0; j < 8; j++) acc[j] = 0.f;
#pragma unroll
    for (int r = 0; r < 16; r++) {
        int t = r * 8 + g;
        float wt = w[t];
        if constexpr (F16SRC) {
            half8 x = *(const half8*)(srch + (size_t)t * DD + c * 8);
#pragma unroll
            for (int j = 0; j < 8; j++) acc[j] += wt * (float)x[j];
        } else {
            const float4v* p = (const float4v*)(srcf + (size_t)t * DD + c * 8);
            float4v x0 = p[0], x1 = p[1];
#pragma unroll
            for (int j = 0; j < 4; j++) { acc[j] += wt * x0[j]; acc[4 + j] += wt * x1[j]; }
        }
    }
#pragma unroll
    for (int j = 0; j < 8; j++) sm[g * DD + c * 8 + j] = acc[j];
    __syncthreads();
    float s = 0.f;
#pragma unroll
    for (int g2 = 0; g2 < 8; g2++) s += sm[g2 * DD + tid];
    atomicAdd(dst + tid, s);
}

extern "C" void kernel_launch(void* const* d_in, const int* in_sizes, int n_in,
                              void* d_out, int out_size, void* d_ws, size_t ws_size,
                              hipStream_t stream) {
    (void)in_sizes; (void)n_in; (void)out_size;
    const float* doc = (const float*)d_in[0];
    const float* qry = (const float*)d_in[1];
    const float* dmask = (const float*)d_in[2];
    const float* qmask = (const float*)d_in[3];
    float* out = (float*)d_out;

    float* pa = (float*)d_ws;                   // [4][B][LD]
    float* pb = pa + 4 * BB * LD;               // [16][B][LQ]
    float* alpha = pb + 16 * BB * LQ;           // [B][LD]
    float* beta = alpha + BB * LD;              // [B][LQ]
    _Float16* dh = (_Float16*)(beta + BB * LQ); // [B][LD][D] f16
    _Float16* qh = dh + (size_t)BB * LD * DD;   // [B][LQ][D] f16
    size_t needed = (size_t)(4 * BB * LD + 16 * BB * LQ + BB * LD + BB * LQ) * 4 +
                    ((size_t)BB * LD * DD + (size_t)BB * LQ * DD) * 2;
    bool useF16 = ws_size >= needed;

    if (useF16) {
        kconv<<<(DOCN8 + QRYN8) / 256, 256, 0, stream>>>(doc, qry, dh, qh);
        k1<true><<<dim3(LQ / BM, LD / BN, BB), 256, 0, stream>>>(qh, dh, pa, pb);
    } else {
        k1<false><<<dim3(LQ / BM, LD / BN, BB), 256, 0, stream>>>(qry, doc, pa, pb);
    }
    k2<<<2 * BB, 256, 0, stream>>>(pa, pb, dmask, qmask, alpha, beta, out);
    if (useF16) {
        k3<true><<<BB * 16 + BB * 4, 256, 0, stream>>>(doc, qry, dh, qh, alpha, beta, out);
    } else {
        k3<false><<<BB * 16 + BB * 4, 256, 0, stream>>>(doc, qry, dh, qh, alpha, beta, out);
    }
}

// Round 7
// 157.649 us; speedup vs baseline: 1.0953x; 1.0137x over previous
//
#include <hip/hip_runtime.h>
#include <hip/hip_bf16.h>
#include <cstdint>

#define BB 32
#define LD 2048
#define LQ 512
#define DD 256
#define BM 128
#define BN 128
#define BK 64

typedef _Float16 half8 __attribute__((ext_vector_type(8)));
typedef _Float16 half4 __attribute__((ext_vector_type(4)));
typedef float float4v __attribute__((ext_vector_type(4)));

// tanh(x) = 1 - 2/(exp2(2*log2e*x)+1); v_exp_f32 + v_rcp_f32. Saturates correctly at +-inf.
__device__ __forceinline__ float tanh_fast(float x) {
    float t = __builtin_amdgcn_exp2f(x * 2.885390081777927f); // 2*log2(e)
    float r = __builtin_amdgcn_rcpf(t + 1.0f);
    return fmaf(-2.0f, r, 1.0f);
}

// async 16B global->LDS; LDS dest = wave-uniform base + lane*16 (HW adds lane offset)
__device__ __forceinline__ void load_lds16(const void* g, void* s) {
    __builtin_amdgcn_global_load_lds((const __attribute__((address_space(1))) void*)g,
                                     (__attribute__((address_space(3))) void*)s, 16, 0, 0);
}

#define DOCN8 (BB * LD * DD / 8)
#define QRYN8 (BB * LQ * DD / 8)

// fp32 -> f16 convert of doc then query, one dispatch, 8 elems/thread. HBM-roofline streaming.
__global__ __launch_bounds__(256) void kconv(const float* __restrict__ doc,
                                             const float* __restrict__ qry,
                                             _Float16* __restrict__ dh,
                                             _Float16* __restrict__ qh) {
    int i = blockIdx.x * 256 + threadIdx.x;
    const float* src;
    _Float16* dst;
    int idx;
    if (i < DOCN8) { src = doc; dst = dh; idx = i; }
    else           { src = qry; dst = qh; idx = i - DOCN8; }
    const float4v* s = (const float4v*)src + (size_t)idx * 2;
    float4v a = s[0], c = s[1];
    half8 h = {(_Float16)a[0], (_Float16)a[1], (_Float16)a[2], (_Float16)a[3],
               (_Float16)c[0], (_Float16)c[1], (_Float16)c[2], (_Float16)c[3]};
    *((half8*)dst + idx) = h;
}

// K1: per-batch tanh(Q Doc^T), fused row/col sums -> PARTIAL logits.
// 128x128 tile, 512 threads = 8 waves as 4(row-groups)x2(col-halves): each wave 32x64
// => 2x4 MFMA 16x16x32 tiles, only 32 AGPR acc + ~70 VGPR -> <=128 regs/wave
// -> 16 waves/CU (2 blocks/CU), double R2's occupancy. f16 global_load_lds DMA staging.
// LDS XOR-swizzle (0 conflicts measured): 8-f16 group g of row r at phys chunk g^(r&7),
// arranged via the lane->global map (LDS side of DMA is fixed base+16*lane).
template <bool F16SRC>
__global__ __launch_bounds__(512, 4) void k1(const void* __restrict__ qsrc,
                                             const void* __restrict__ dsrc,
                                             float* __restrict__ pa,   // [4][B][LD] col-sum partials
                                             float* __restrict__ pb) { // [16][B][LQ] row-sum partials
    __shared__ _Float16 sQ[BM * BK]; // 16KB
    __shared__ _Float16 sD[BN * BK]; // 16KB
    __shared__ float srow[BM][2];    // by wc
    __shared__ float scol[BN][4];    // by wr
    const int bq = blockIdx.x, bt = blockIdx.y, b = blockIdx.z;
    const int tid = threadIdx.x;
    const int lane = tid & 63;
    const int wave = tid >> 6;       // 0..7
    const int r16 = lane & 15;
    const int q4 = lane >> 4;
    const int wr = wave >> 1, wc = wave & 1;
    const int mb = wr * 32, nb = wc * 64;

    float4v acc[2][4];
    float4v zero = {0.f, 0.f, 0.f, 0.f};
#pragma unroll
    for (int m = 0; m < 2; m++)
#pragma unroll
        for (int n = 0; n < 4; n++) acc[m][n] = zero;

    // f16 DMA staging lane map: 1KB chunk = 8 rows x 128B
    const int lrow = lane >> 3;                 // 0..7
    const int lcol = ((lane & 7) ^ lrow) * 8;   // logical k offset (f16) for this phys pos

    for (int kk = 0; kk < DD; kk += BK) {
        __syncthreads(); // previous iteration's LDS reads done
        if constexpr (F16SRC) {
            const _Float16* Qh = (const _Float16*)qsrc + ((size_t)b * LQ + bq * BM) * DD;
            const _Float16* Dh = (const _Float16*)dsrc + ((size_t)b * LD + bt * BN) * DD;
#pragma unroll
            for (int j = 0; j < 2; j++) {
                int c = wave * 2 + j;           // chunk 0..15 (rows 8c..8c+7)
                int row = 8 * c + lrow;
                load_lds16(Qh + (size_t)row * DD + kk + lcol, &sQ[c * 512]);
                load_lds16(Dh + (size_t)row * DD + kk + lcol, &sD[c * 512]);
            }
        } else {
            const float* Qf = (const float*)qsrc + ((size_t)b * LQ + bq * BM) * DD;
            const float* Df = (const float*)dsrc + ((size_t)b * LD + bt * BN) * DD;
#pragma unroll
            for (int i = 0; i < 4; i++) {
                int f = tid + 512 * i;          // float4 id within 128x64 tile
                int row = f >> 4, c = f & 15;
                int c2 = c >> 1, hlf = c & 1;
                int p = c2 ^ (row & 7);
                float4v v = *(const float4v*)(Qf + (size_t)row * DD + kk + 4 * c);
                half4 h = {(_Float16)v[0], (_Float16)v[1], (_Float16)v[2], (_Float16)v[3]};
                *(half4*)(&sQ[row * BK + p * 8 + hlf * 4]) = h;
                float4v w = *(const float4v*)(Df + (size_t)row * DD + kk + 4 * c);
                half4 h2 = {(_Float16)w[0], (_Float16)w[1], (_Float16)w[2], (_Float16)w[3]};
                *(half4*)(&sD[row * BK + p * 8 + hlf * 4]) = h2;
            }
        }
        __syncthreads(); // staging complete

#pragma unroll
        for (int kk2 = 0; kk2 < 2; kk2++) {
            const int sw = ((4 * kk2 + q4) ^ (r16 & 7)) * 8;
            half8 af[2], bf[4];
#pragma unroll
            for (int m = 0; m < 2; m++) af[m] = *(const half8*)(&sQ[(mb + 16 * m + r16) * BK + sw]);
#pragma unroll
            for (int n = 0; n < 4; n++) bf[n] = *(const half8*)(&sD[(nb + 16 * n + r16) * BK + sw]);
#pragma unroll
            for (int m = 0; m < 2; m++)
#pragma unroll
                for (int n = 0; n < 4; n++)
                    acc[m][n] = __builtin_amdgcn_mfma_f32_16x16x32_f16(af[m], bf[n], acc[m][n], 0, 0, 0);
        }
    }

    // Epilogue. C/D layout: row = 4*q4 + r, col = r16.
    float rsum[2][4];
    float csum[4];
#pragma unroll
    for (int m = 0; m < 2; m++)
#pragma unroll
        for (int r = 0; r < 4; r++) rsum[m][r] = 0.f;
#pragma unroll
    for (int n = 0; n < 4; n++) csum[n] = 0.f;

#pragma unroll
    for (int m = 0; m < 2; m++)
#pragma unroll
        for (int n = 0; n < 4; n++) {
            float t0 = tanh_fast(acc[m][n][0]);
            float t1 = tanh_fast(acc[m][n][1]);
            float t2 = tanh_fast(acc[m][n][2]);
            float t3 = tanh_fast(acc[m][n][3]);
            csum[n] += t0 + t1 + t2 + t3;
            rsum[m][0] += t0;
            rsum[m][1] += t1;
            rsum[m][2] += t2;
            rsum[m][3] += t3;
        }

    // row sums over the wave's 64 cols: butterfly across r16; lanes r16<4 commit rows 4q4+r16
#pragma unroll
    for (int m = 0; m < 2; m++) {
#pragma unroll
        for (int r = 0; r < 4; r++) {
            float v = rsum[m][r];
            v += __shfl_xor(v, 1);
            v += __shfl_xor(v, 2);
            v += __shfl_xor(v, 4);
            v += __shfl_xor(v, 8);
            rsum[m][r] = v;
        }
        if (r16 < 4) {
            float v = (r16 == 0) ? rsum[m][0] : (r16 == 1) ? rsum[m][1] : (r16 == 2) ? rsum[m][2] : rsum[m][3];
            srow[mb + 16 * m + 4 * q4 + r16][wc] = v;
        }
    }
    // col sums over the wave's 32 rows (both m-tiles already in csum): butterfly across q4
#pragma unroll
    for (int n = 0; n < 4; n++) {
        float v = csum[n];
        v += __shfl_xor(v, 16);
        v += __shfl_xor(v, 32);
        if (lane < 16) scol[nb + 16 * n + lane][wr] = v;
    }
    __syncthreads();
    if (tid < 128) {
        float v = srow[tid][0] + srow[tid][1];
        pb[((size_t)bt * BB + b) * LQ + bq * BM + tid] = v;
        float u = scol[tid][0] + scol[tid][1] + scol[tid][2] + scol[tid][3];
        pa[((size_t)bq * BB + b) * LD + bt * BN + tid] = u;
    }
}

// K2: sum partials -> masked renormalized softmax. Blocks 0..31: alpha rows (n=2048, also
// zero d_out slice for k3's atomics); blocks 32..63: beta rows (n=512).
__global__ __launch_bounds__(256) void k2(const float* __restrict__ pa, const float* __restrict__ pb,
                                          const float* __restrict__ dmask, const float* __restrict__ qmask,
                                          float* __restrict__ alpha, float* __restrict__ beta,
                                          float* __restrict__ out) {
    __shared__ float sl[2048];
    __shared__ float sm[4], ss[4];
    int blk = blockIdx.x, tid = threadIdx.x, lane = tid & 63, wave = tid >> 6;
    const float* mk;
    float* dst;
    int n;
    if (blk < BB) {
        int b = blk;
        out[b * 2 * DD + tid] = 0.f;          // zero d_out for k3
        out[b * 2 * DD + 256 + tid] = 0.f;
        n = LD;
        mk = dmask + b * LD;
        dst = alpha + b * LD;
        for (int i = tid; i < n; i += 256) {
            float s = 0.f;
#pragma unroll
            for (int j = 0; j < 4; j++) s += pa[((size_t)j * BB + b) * LD + i];
            sl[i] = s;
        }
    } else {
        int b = blk - BB;
        n = LQ;
        mk = qmask + b * LQ;
        dst = beta + b * LQ;
        for (int i = tid; i < n; i += 256) {
            float s = 0.f;
#pragma unroll
            for (int j = 0; j < 16; j++) s += pb[((size_t)j * BB + b) * LQ + i];
            sl[i] = s;
        }
    }
    __syncthreads();
    float mx = -3.0e38f;
    for (int i = tid; i < n; i += 256) mx = fmaxf(mx, sl[i]);
#pragma unroll
    for (int s = 1; s < 64; s <<= 1) mx = fmaxf(mx, __shfl_xor(mx, s));
    if (lane == 0) sm[wave] = mx;
    __syncthreads();
    mx = fmaxf(fmaxf(sm[0], sm[1]), fmaxf(sm[2], sm[3]));
    const float L2E = 1.4426950408889634f;
    float sum = 0.f;
    for (int i = tid; i < n; i += 256) {
        float e = __builtin_amdgcn_exp2f((sl[i] - mx) * L2E) * mk[i];
        sl[i] = e;
        sum += e;
    }
#pragma unroll
    for (int s = 1; s < 64; s <<= 1) sum += __shfl_xor(sum, s);
    if (lane == 0) ss[wave] = sum;
    __syncthreads();
    sum = ss[0] + ss[1] + ss[2] + ss[3];
    float inv = 1.0f / sum;
    for (int i = tid; i < n; i += 256) dst[i] = sl[i] * inv;
}

// K3: weighted pooling. f16 sources when available (half the bytes), coalesced 16B loads.
// Block = (b, 128-position chunk); thread (g=tid>>5, c=tid&31) owns d-slice [8c,8c+8).
template <bool F16SRC>
__global__ __launch_bounds__(256) void k3(const float* __restrict__ docf, const float* __restrict__ qryf,
                                          const _Float16* __restrict__ dh, const _Float16* __restrict__ qh,
                                          const float* __restrict__ alpha, const float* __restrict__ beta,
                                          float* __restrict__ out) {
    __shared__ float sm[8 * DD];
    int blk = blockIdx.x, tid = threadIdx.x;
    const float* srcf;
    const _Float16* srch;
    const float* w;
    float* dst;
    if (blk < BB * 16) {
        int b = blk >> 4, ch = blk & 15;
        srcf = docf + ((size_t)b * LD + ch * 128) * DD;
        srch = dh + ((size_t)b * LD + ch * 128) * DD;
        w = alpha + b * LD + ch * 128;
        dst = out + b * 2 * DD;
    } else {
        int k = blk - BB * 16;
        int b = k >> 2, ch = k & 3;
        srcf = qryf + ((size_t)b * LQ + ch * 128) * DD;
        srch = qh + ((size_t)b * LQ + ch * 128) * DD;
        w = beta + b * LQ + ch * 128;
        dst = out + b * 2 * DD + DD;
    }
    int g = tid >> 5, c = tid & 31;
    float acc[8];
#pragma unroll
    for (int j = 0; j < 8; j++) acc[j] = 0.f;
#pragma unroll
    for (int r = 0; r < 16; r++) {
        int t = r * 8 + g;
        float wt = w[t];
        if constexpr (F16SRC) {
            half8 x = *(const half8*)(srch + (size_t)t * DD + c * 8);
#pragma unroll
            for (int j = 0; j < 8; j++) acc[j] += wt * (float)x[j];
        } else {
            const float4v* p = (const float4v*)(srcf + (size_t)t * DD + c * 8);
            float4v x0 = p[0], x1 = p[1];
#pragma unroll
            for (int j = 0; j < 4; j++) { acc[j] += wt * x0[j]; acc[4 + j] += wt * x1[j]; }
        }
    }
#pragma unroll
    for (int j = 0; j < 8; j++) sm[g * DD + c * 8 + j] = acc[j];
    __syncthreads();
    float s = 0.f;
#pragma unroll
    for (int g2 = 0; g2 < 8; g2++) s += sm[g2 * DD + tid];
    atomicAdd(dst + tid, s);
}

extern "C" void kernel_launch(void* const* d_in, const int* in_sizes, int n_in,
                              void* d_out, int out_size, void* d_ws, size_t ws_size,
                              hipStream_t stream) {
    (void)in_sizes; (void)n_in; (void)out_size;
    const float* doc = (const float*)d_in[0];
    const float* qry = (const float*)d_in[1];
    const float* dmask = (const float*)d_in[2];
    const float* qmask = (const float*)d_in[3];
    float* out = (float*)d_out;

    float* pa = (float*)d_ws;                   // [4][B][LD]
    float* pb = pa + 4 * BB * LD;               // [16][B][LQ]
    float* alpha = pb + 16 * BB * LQ;           // [B][LD]
    float* beta = alpha + BB * LD;              // [B][LQ]
    _Float16* dh = (_Float16*)(beta + BB * LQ); // [B][LD][D] f16
    _Float16* qh = dh + (size_t)BB * LD * DD;   // [B][LQ][D] f16
    size_t needed = (size_t)(4 * BB * LD + 16 * BB * LQ + BB * LD + BB * LQ) * 4 +
                    ((size_t)BB * LD * DD + (size_t)BB * LQ * DD) * 2;
    bool useF16 = ws_size >= needed;

    if (useF16) {
        kconv<<<(DOCN8 + QRYN8) / 256, 256, 0, stream>>>(doc, qry, dh, qh);
        k1<true><<<dim3(LQ / BM, LD / BN, BB), 512, 0, stream>>>(qh, dh, pa, pb);
    } else {
        k1<false><<<dim3(LQ / BM, LD / BN, BB), 512, 0, stream>>>(qry, doc, pa, pb);
    }
    k2<<<2 * BB, 256, 0, stream>>>(pa, pb, dmask, qmask, alpha, beta, out);
    if (useF16) {
        k3<true><<<BB * 16 + BB * 4, 256, 0, stream>>>(doc, qry, dh, qh, alpha, beta, out);
    } else {
        k3<false><<<BB * 16 + BB * 4, 256, 0, stream>>>(doc, qry, dh, qh, alpha, beta, out);
    }
}

// Round 8
// 156.986 us; speedup vs baseline: 1.0999x; 1.0042x over previous
//
#include <hip/hip_runtime.h>
#include <hip/hip_bf16.h>
#include <cstdint>

#define BB 32
#define LD 2048
#define LQ 512
#define DD 256
#define BM 128
#define BN 128
#define BK 64

typedef _Float16 half8 __attribute__((ext_vector_type(8)));
typedef _Float16 half4 __attribute__((ext_vector_type(4)));
typedef float float4v __attribute__((ext_vector_type(4)));

// tanh(x) = 1 - 2/(exp2(2*log2e*x)+1); v_exp_f32 + v_rcp_f32. Saturates correctly at +-inf.
__device__ __forceinline__ float tanh_fast(float x) {
    float t = __builtin_amdgcn_exp2f(x * 2.885390081777927f); // 2*log2(e)
    float r = __builtin_amdgcn_rcpf(t + 1.0f);
    return fmaf(-2.0f, r, 1.0f);
}

// async 16B global->LDS; LDS dest = wave-uniform base + lane*16 (HW adds lane offset)
__device__ __forceinline__ void load_lds16(const void* g, void* s) {
    __builtin_amdgcn_global_load_lds((const __attribute__((address_space(1))) void*)g,
                                     (__attribute__((address_space(3))) void*)s, 16, 0, 0);
}

#define DOCN8 (BB * LD * DD / 8)
#define QRYN8 (BB * LQ * DD / 8)

// fp32 -> f16 convert of doc then query, one dispatch, 8 elems/thread. HBM-roofline streaming.
__global__ __launch_bounds__(256) void kconv(const float* __restrict__ doc,
                                             const float* __restrict__ qry,
                                             _Float16* __restrict__ dh,
                                             _Float16* __restrict__ qh) {
    int i = blockIdx.x * 256 + threadIdx.x;
    const float* src;
    _Float16* dst;
    int idx;
    if (i < DOCN8) { src = doc; dst = dh; idx = i; }
    else           { src = qry; dst = qh; idx = i - DOCN8; }
    const float4v* s = (const float4v*)src + (size_t)idx * 2;
    float4v a = s[0], c = s[1];
    half8 h = {(_Float16)a[0], (_Float16)a[1], (_Float16)a[2], (_Float16)a[3],
               (_Float16)c[0], (_Float16)c[1], (_Float16)c[2], (_Float16)c[3]};
    *((half8*)dst + idx) = h;
}

// K1: per-batch tanh(Q Doc^T), fused row/col sums -> PARTIAL logits.
// 128x128 tile, 4 waves (64x64 quadrants: best LDS-bytes/FLOP = 0.03), BK=64, f16 DMA staging.
// __launch_bounds__(256,4): budget 128 regs/wave = 64 AGPR acc + <=64 arch VGPR
// -> 4 waves/SIMD (16 waves/CU), double R2's occupancy at half R7's LDS traffic.
// LDS XOR-swizzle (0 conflicts measured): 8-f16 group g of row r at phys chunk g^(r&7).
template <bool F16SRC>
__global__ __launch_bounds__(256, 4) void k1(const void* __restrict__ qsrc,
                                             const void* __restrict__ dsrc,
                                             float* __restrict__ pa,   // [4][B][LD] col-sum partials
                                             float* __restrict__ pb) { // [16][B][LQ] row-sum partials
    __shared__ _Float16 sQ[BM * BK]; // 16KB
    __shared__ _Float16 sD[BN * BK]; // 16KB
    __shared__ float srow[BM][2];
    __shared__ float scol[BN][2];
    const int bq = blockIdx.x, bt = blockIdx.y, b = blockIdx.z;
    const int tid = threadIdx.x;
    const int lane = tid & 63;
    const int wave = tid >> 6;
    const int r16 = lane & 15;
    const int q4 = lane >> 4;
    const int mb = (wave >> 1) * 64, nb = (wave & 1) * 64;

    float4v acc[4][4];
    float4v zero = {0.f, 0.f, 0.f, 0.f};
#pragma unroll
    for (int m = 0; m < 4; m++)
#pragma unroll
        for (int n = 0; n < 4; n++) acc[m][n] = zero;

    // f16 DMA staging lane map: 1KB chunk = 8 rows x 128B
    const int lrow = lane >> 3;                 // 0..7
    const int lcol = ((lane & 7) ^ lrow) * 8;   // logical k offset (f16) for this phys pos

    for (int kk = 0; kk < DD; kk += BK) {
        __syncthreads(); // previous iteration's LDS reads done
        if constexpr (F16SRC) {
            const _Float16* Qh = (const _Float16*)qsrc + ((size_t)b * LQ + bq * BM) * DD;
            const _Float16* Dh = (const _Float16*)dsrc + ((size_t)b * LD + bt * BN) * DD;
#pragma unroll
            for (int j = 0; j < 4; j++) {
                int c = wave * 4 + j;           // chunk 0..15 (rows 8c..8c+7)
                int row = 8 * c + lrow;
                load_lds16(Qh + (size_t)row * DD + kk + lcol, &sQ[c * 512]);
                load_lds16(Dh + (size_t)row * DD + kk + lcol, &sD[c * 512]);
            }
        } else {
            const float* Qf = (const float*)qsrc + ((size_t)b * LQ + bq * BM) * DD;
            const float* Df = (const float*)dsrc + ((size_t)b * LD + bt * BN) * DD;
#pragma unroll
            for (int i = 0; i < 8; i++) {
                int f = tid + 256 * i;          // float4 id within 128x64 tile
                int row = f >> 4, c = f & 15;
                int c2 = c >> 1, hlf = c & 1;
                int p = c2 ^ (row & 7);
                float4v v = *(const float4v*)(Qf + (size_t)row * DD + kk + 4 * c);
                half4 h = {(_Float16)v[0], (_Float16)v[1], (_Float16)v[2], (_Float16)v[3]};
                *(half4*)(&sQ[row * BK + p * 8 + hlf * 4]) = h;
                float4v w = *(const float4v*)(Df + (size_t)row * DD + kk + 4 * c);
                half4 h2 = {(_Float16)w[0], (_Float16)w[1], (_Float16)w[2], (_Float16)w[3]};
                *(half4*)(&sD[row * BK + p * 8 + hlf * 4]) = h2;
            }
        }
        __syncthreads(); // staging complete

#pragma unroll
        for (int kk2 = 0; kk2 < 2; kk2++) {
            const int sw = ((4 * kk2 + q4) ^ (r16 & 7)) * 8;
            half8 af[4], bf[4];
#pragma unroll
            for (int m = 0; m < 4; m++) af[m] = *(const half8*)(&sQ[(mb + 16 * m + r16) * BK + sw]);
#pragma unroll
            for (int n = 0; n < 4; n++) bf[n] = *(const half8*)(&sD[(nb + 16 * n + r16) * BK + sw]);
#pragma unroll
            for (int m = 0; m < 4; m++)
#pragma unroll
                for (int n = 0; n < 4; n++)
                    acc[m][n] = __builtin_amdgcn_mfma_f32_16x16x32_f16(af[m], bf[n], acc[m][n], 0, 0, 0);
        }
    }

    // Epilogue. C/D layout: row = 4*q4 + r, col = r16.
    float rsum[4][4];
    float csum[4];
#pragma unroll
    for (int m = 0; m < 4; m++)
#pragma unroll
        for (int r = 0; r < 4; r++) rsum[m][r] = 0.f;
#pragma unroll
    for (int n = 0; n < 4; n++) csum[n] = 0.f;

#pragma unroll
    for (int m = 0; m < 4; m++)
#pragma unroll
        for (int n = 0; n < 4; n++) {
            float t0 = tanh_fast(acc[m][n][0]);
            float t1 = tanh_fast(acc[m][n][1]);
            float t2 = tanh_fast(acc[m][n][2]);
            float t3 = tanh_fast(acc[m][n][3]);
            csum[n] += t0 + t1 + t2 + t3;
            rsum[m][0] += t0;
            rsum[m][1] += t1;
            rsum[m][2] += t2;
            rsum[m][3] += t3;
        }

#pragma unroll
    for (int m = 0; m < 4; m++) {
#pragma unroll
        for (int r = 0; r < 4; r++) {
            float v = rsum[m][r];
            v += __shfl_xor(v, 1);
            v += __shfl_xor(v, 2);
            v += __shfl_xor(v, 4);
            v += __shfl_xor(v, 8);
            rsum[m][r] = v;
        }
        if (r16 < 4) {
            float v = (r16 == 0) ? rsum[m][0] : (r16 == 1) ? rsum[m][1] : (r16 == 2) ? rsum[m][2] : rsum[m][3];
            srow[mb + 16 * m + 4 * q4 + r16][wave & 1] = v;
        }
    }
#pragma unroll
    for (int n = 0; n < 4; n++) {
        float v = csum[n];
        v += __shfl_xor(v, 16);
        v += __shfl_xor(v, 32);
        if (lane < 16) scol[nb + 16 * n + lane][wave >> 1] = v;
    }
    __syncthreads();
    if (tid < 128) {
        float v = srow[tid][0] + srow[tid][1];
        pb[((size_t)bt * BB + b) * LQ + bq * BM + tid] = v;
        float u = scol[tid][0] + scol[tid][1];
        pa[((size_t)bq * BB + b) * LD + bt * BN + tid] = u;
    }
}

// K23: fused softmax + pooling, atomic-free, writes d_out directly (no zeroing needed).
// 256 blocks: blk<128 -> doc (b=blk>>2, d-chunk=blk&3 of 64); else query likewise.
// Each block: reduce its logit row from partials -> max -> masked exp (weights in LDS)
// -> pool its 64-d slice with coalesced 16B loads -> write disjoint out slice * 1/sum.
template <bool F16SRC>
__global__ __launch_bounds__(256) void k23(const float* __restrict__ pa, const float* __restrict__ pb,
                                           const float* __restrict__ dmask, const float* __restrict__ qmask,
                                           const float* __restrict__ docf, const float* __restrict__ qryf,
                                           const _Float16* __restrict__ dh, const _Float16* __restrict__ qh,
                                           float* __restrict__ out) {
    __shared__ float sl[2048];
    __shared__ float sred[32][64];
    __shared__ float sm[4], ss[4];
    const int blk = blockIdx.x, tid = threadIdx.x, lane = tid & 63, wave = tid >> 6;
    const bool isdoc = blk < 128;
    const int k = isdoc ? blk : blk - 128;
    const int b = k >> 2, dc = k & 3;
    const int n = isdoc ? LD : LQ;
    const float* mk = isdoc ? dmask + (size_t)b * LD : qmask + (size_t)b * LQ;

    if (isdoc) {
        for (int i = tid; i < n; i += 256) {
            float s = 0.f;
#pragma unroll
            for (int j = 0; j < 4; j++) s += pa[((size_t)j * BB + b) * LD + i];
            sl[i] = s;
        }
    } else {
        for (int i = tid; i < n; i += 256) {
            float s = 0.f;
#pragma unroll
            for (int j = 0; j < 16; j++) s += pb[((size_t)j * BB + b) * LQ + i];
            sl[i] = s;
        }
    }
    __syncthreads();
    float mx = -3.0e38f;
    for (int i = tid; i < n; i += 256) mx = fmaxf(mx, sl[i]);
#pragma unroll
    for (int s = 1; s < 64; s <<= 1) mx = fmaxf(mx, __shfl_xor(mx, s));
    if (lane == 0) sm[wave] = mx;
    __syncthreads();
    mx = fmaxf(fmaxf(sm[0], sm[1]), fmaxf(sm[2], sm[3]));
    const float L2E = 1.4426950408889634f;
    float sum = 0.f;
    for (int i = tid; i < n; i += 256) {
        float e = __builtin_amdgcn_exp2f((sl[i] - mx) * L2E) * mk[i];
        sl[i] = e;  // unnormalized weight
        sum += e;
    }
#pragma unroll
    for (int s = 1; s < 64; s <<= 1) sum += __shfl_xor(sum, s);
    if (lane == 0) ss[wave] = sum;
    __syncthreads();
    sum = ss[0] + ss[1] + ss[2] + ss[3];
    const float inv = 1.0f / sum;

    // pooling: thread (pg=tid>>3 of 32, c8=tid&7 of 8): positions pg*per..+per, d-cols c8*8..+8
    const int c8 = tid & 7, pg = tid >> 3;
    const int per = n >> 5; // 64 (doc) or 16 (query)
    float acc[8];
#pragma unroll
    for (int j = 0; j < 8; j++) acc[j] = 0.f;
    const int dof = dc * 64 + c8 * 8;
    if constexpr (F16SRC) {
        const _Float16* src = (isdoc ? dh + (size_t)b * LD * DD : qh + (size_t)b * LQ * DD) + dof;
        for (int r = 0; r < per; r++) {
            int t = pg * per + r;
            float wt = sl[t];
            half8 x = *(const half8*)(src + (size_t)t * DD);
#pragma unroll
            for (int j = 0; j < 8; j++) acc[j] += wt * (float)x[j];
        }
    } else {
        const float* src = (isdoc ? docf + (size_t)b * LD * DD : qryf + (size_t)b * LQ * DD) + dof;
        for (int r = 0; r < per; r++) {
            int t = pg * per + r;
            float wt = sl[t];
            const float4v* p = (const float4v*)(src + (size_t)t * DD);
            float4v x0 = p[0], x1 = p[1];
#pragma unroll
            for (int j = 0; j < 4; j++) { acc[j] += wt * x0[j]; acc[4 + j] += wt * x1[j]; }
        }
    }
#pragma unroll
    for (int j = 0; j < 8; j++) sred[pg][c8 * 8 + j] = acc[j];
    __syncthreads();
    if (tid < 64) {
        float s = 0.f;
#pragma unroll
        for (int g = 0; g < 32; g++) s += sred[g][tid];
        out[(size_t)b * 2 * DD + (isdoc ? 0 : DD) + dc * 64 + tid] = s * inv;
    }
}

extern "C" void kernel_launch(void* const* d_in, const int* in_sizes, int n_in,
                              void* d_out, int out_size, void* d_ws, size_t ws_size,
                              hipStream_t stream) {
    (void)in_sizes; (void)n_in; (void)out_size;
    const float* doc = (const float*)d_in[0];
    const float* qry = (const float*)d_in[1];
    const float* dmask = (const float*)d_in[2];
    const float* qmask = (const float*)d_in[3];
    float* out = (float*)d_out;

    float* pa = (float*)d_ws;                   // [4][B][LD]
    float* pb = pa + 4 * BB * LD;               // [16][B][LQ]
    _Float16* dh = (_Float16*)(pb + 16 * BB * LQ); // [B][LD][D] f16
    _Float16* qh = dh + (size_t)BB * LD * DD;      // [B][LQ][D] f16
    size_t needed = (size_t)(4 * BB * LD + 16 * BB * LQ) * 4 +
                    ((size_t)BB * LD * DD + (size_t)BB * LQ * DD) * 2;
    bool useF16 = ws_size >= needed;

    if (useF16) {
        kconv<<<(DOCN8 + QRYN8) / 256, 256, 0, stream>>>(doc, qry, dh, qh);
        k1<true><<<dim3(LQ / BM, LD / BN, BB), 256, 0, stream>>>(qh, dh, pa, pb);
        k23<true><<<256, 256, 0, stream>>>(pa, pb, dmask, qmask, doc, qry, dh, qh, out);
    } else {
        k1<false><<<dim3(LQ / BM, LD / BN, BB), 256, 0, stream>>>(qry, doc, pa, pb);
        k23<false><<<256, 256, 0, stream>>>(pa, pb, dmask, qmask, doc, qry, dh, qh, out);
    }
}